// Round 7
// baseline (674.301 us; speedup 1.0000x reference)
//
#include <hip/hip_runtime.h>
#include <hip/hip_cooperative_groups.h>
#include <math.h>

namespace cg = cooperative_groups;

#define NR   2048
#define XD   512
#define HID  300
#define BS   256
#define NPAD 320
#define KTOT 1024
#define GSTR 304          // row stride for GPB/P0a/P0b (float4-aligned)
#define GRID 1024

typedef __attribute__((ext_vector_type(8))) short bf16x8;
typedef __attribute__((ext_vector_type(4))) float f32x4;

__device__ __forceinline__ float softplus_f(float x) {
    return fmaxf(x, 0.f) + log1pf(__expf(-fabsf(x)));
}
__device__ __forceinline__ unsigned short f2bf(float f) {
    unsigned int u = __float_as_uint(f);
    u += 0x7FFFu + ((u >> 16) & 1u);   // RNE
    return (unsigned short)(u >> 16);
}

// One cooperative kernel, 1024 blocks x 256 threads, 4 phases:
//  A: fp32->bf16 convert (A matrices + W1 transpose)
//  B: 2560 MFMA wave-tiles (LP4 / GPB / P0a / P0b)
//  C: neg term (unit = chunk,g0 of 4; 2 blocks split k) + pos rows (2/block)
//  D: block 0 deterministic final reduce
__global__ __launch_bounds__(256, 4) void infonce_all(
    const float* __restrict__ pl, const float* __restrict__ pg,
    const float* __restrict__ nl, const float* __restrict__ ng,
    const float* __restrict__ W1, const float* __restrict__ b1,
    const float* __restrict__ W2, const float* __restrict__ b2,
    unsigned short* __restrict__ Aneg, unsigned short* __restrict__ Apos,
    unsigned short* __restrict__ Wt,
    float* __restrict__ LP4, float* __restrict__ GPB,
    float* __restrict__ P0a, float* __restrict__ P0b,
    float* __restrict__ negE, float* __restrict__ posP,
    float* __restrict__ out)
{
    cg::grid_group gg = cg::this_grid();
    const int tid = threadIdx.x, bid = blockIdx.x;
    const int wid = tid >> 6, lane = tid & 63;

    __shared__ unsigned short ts[16][72];
    __shared__ __align__(16) float w2s[HID];
    __shared__ __align__(16) float gbs[4][HID];
    __shared__ __align__(16) float pacc[2][128][4];
    __shared__ float red[2][4];
    __shared__ float redp[2];
    __shared__ float fin[4];

    // ---------------- Phase A: convert ----------------
    for (int u = bid; u < 4416; u += GRID) {
        if (u < 4096) {
            const int m = (u < 2048) ? u : u - 2048;
            const float* lo = (u < 2048) ? nl : pl;
            const float* hi = (u < 2048) ? ng : pg;
            unsigned short* dst = (u < 2048) ? Aneg : Apos;
            const int kq = tid * 4;
            const float4 v = (kq < XD) ? *(const float4*)(lo + m * XD + kq)
                                       : *(const float4*)(hi + m * XD + kq - XD);
            ushort4 o;
            o.x = f2bf(v.x); o.y = f2bf(v.y); o.z = f2bf(v.z); o.w = f2bf(v.w);
            *(ushort4*)(dst + m * KTOT + kq) = o;
        } else {
            // W1 [1024][300] -> Wt [320][1024] bf16 (zero-pad rows 300..319)
            const int t = u - 4096;
            const int nt = t % 20, kt = t / 20;
            const int n = nt * 16 + (tid & 15);
            const int kl = tid >> 4;
            #pragma unroll
            for (int j = 0; j < 4; ++j) {
                const int k = kt * 64 + kl * 4 + j;
                ts[tid & 15][kl * 4 + j] = f2bf((n < HID) ? W1[k * HID + n] : 0.f);
            }
            __syncthreads();
            const int nw = tid >> 4, kw = (tid & 15) * 4;
            ushort4 o;
            o.x = ts[nw][kw];     o.y = ts[nw][kw + 1];
            o.z = ts[nw][kw + 2]; o.w = ts[nw][kw + 3];
            *(ushort4*)(Wt + (nt * 16 + nw) * KTOT + kt * 64 + kw) = o;
        }
    }
    __threadfence();
    gg.sync();

    // ---------------- Phase B: MFMA GEMMs ----------------
    // wave-unit Wv in [0,2560): job = Wv/640; tile = Wv%640 -> m0,n0
    // job 0: LP4 = nl@W1l (scatter [k/4][l][4]); 1: GPB = ng@W1g + b1;
    // job 2: P0a = pl@W1l; 3: P0b = pg@W1g
    {
        const int Wv = bid * 4 + wid;
        if (Wv < 2560) {
            const int job = Wv / 640, t = Wv % 640;
            const int m0 = (t & 63) * 32, n0 = (t >> 6) * 32;
            const int r = lane & 15, g = lane >> 4;
            const unsigned short* A = (job >= 2) ? Apos : Aneg;
            const int kbeg = (job & 1) ? XD : 0;
            const unsigned short* a0p = A  + (m0 + r) * KTOT + kbeg + 8 * g;
            const unsigned short* a1p = a0p + 16 * KTOT;
            const unsigned short* b0p = Wt + (n0 + r) * KTOT + kbeg + 8 * g;
            const unsigned short* b1p = b0p + 16 * KTOT;

            f32x4 acc00 = {0,0,0,0}, acc01 = {0,0,0,0};
            f32x4 acc10 = {0,0,0,0}, acc11 = {0,0,0,0};
            #pragma unroll 4
            for (int k = 0; k < XD; k += 32) {
                const bf16x8 a0 = *(const bf16x8*)(a0p + k);
                const bf16x8 a1 = *(const bf16x8*)(a1p + k);
                const bf16x8 w0 = *(const bf16x8*)(b0p + k);
                const bf16x8 w1 = *(const bf16x8*)(b1p + k);
                acc00 = __builtin_amdgcn_mfma_f32_16x16x32_bf16(a0, w0, acc00, 0, 0, 0);
                acc01 = __builtin_amdgcn_mfma_f32_16x16x32_bf16(a0, w1, acc01, 0, 0, 0);
                acc10 = __builtin_amdgcn_mfma_f32_16x16x32_bf16(a1, w0, acc10, 0, 0, 0);
                acc11 = __builtin_amdgcn_mfma_f32_16x16x32_bf16(a1, w1, acc11, 0, 0, 0);
            }
            f32x4 accs[2][2] = {{acc00, acc01}, {acc10, acc11}};
            #pragma unroll
            for (int mi = 0; mi < 2; ++mi) {
                #pragma unroll
                for (int ni = 0; ni < 2; ++ni) {
                    const int n = n0 + ni * 16 + r;
                    const int mb = m0 + mi * 16 + 4 * g;
                    const f32x4 v = accs[mi][ni];
                    if (job == 0) {
                        float* base = LP4 + ((size_t)(n >> 2) * NR + mb) * 4 + (n & 3);
                        base[0] = v[0]; base[4] = v[1]; base[8] = v[2]; base[12] = v[3];
                    } else if (n < HID) {
                        const float bias = (job == 1) ? b1[n] : 0.f;
                        float* o = (job == 1) ? GPB : ((job == 2) ? P0a : P0b);
                        #pragma unroll
                        for (int j = 0; j < 4; ++j)
                            o[(size_t)(mb + j) * GSTR + n] = v[j] + bias;
                    }
                }
            }
        }
    }
    __threadfence();
    gg.sync();

    // ---------------- Phase C: neg (k-split) + pos ----------------
    const float b2v = b2[0];
    {
        const int unit = bid >> 1, half = bid & 1;
        const int chunk = unit >> 6, g0 = (unit & 63) * 4;
        const float* gp = GPB + (size_t)(chunk * BS + g0) * GSTR;
        for (int idx = tid; idx < HID; idx += 256) {
            w2s[idx] = W2[idx];
            gbs[0][idx] = gp[idx];
            gbs[1][idx] = gp[GSTR + idx];
            gbs[2][idx] = gp[2 * GSTR + idx];
            gbs[3][idx] = gp[3 * GSTR + idx];
        }
        __syncthreads();

        const int lh = tid & 127, kh = tid >> 7;
        const int lg = chunk * BS + half * 128 + lh;
        const float4* lp4 = (const float4*)LP4 + lg;
        const int k4beg = kh ? 38 : 0;
        const int k4end = kh ? 75 : 38;

        float acc[4] = {0.f, 0.f, 0.f, 0.f};
        // 2-deep register pipeline on the per-lane LP stream
        // (max prefetch index 76 < 80-slot padded LP4).
        float4 a0 = lp4[(size_t)k4beg * NR];
        float4 a1 = lp4[(size_t)(k4beg + 1) * NR];
        for (int k4 = k4beg; k4 < k4end; ++k4) {
            const float4 nx = lp4[(size_t)(k4 + 2) * NR];
            const float4 w4 = *(const float4*)&w2s[k4 * 4];
            #pragma unroll
            for (int gt = 0; gt < 4; ++gt) {
                const float4 g4 = *(const float4*)&gbs[gt][k4 * 4];
                acc[gt] = fmaf(fmaxf(g4.x + a0.x, 0.f), w4.x, acc[gt]);
                acc[gt] = fmaf(fmaxf(g4.y + a0.y, 0.f), w4.y, acc[gt]);
                acc[gt] = fmaf(fmaxf(g4.z + a0.z, 0.f), w4.z, acc[gt]);
                acc[gt] = fmaf(fmaxf(g4.w + a0.w, 0.f), w4.w, acc[gt]);
            }
            a0 = a1; a1 = nx;
        }
        *(float4*)&pacc[kh][lh][0] = make_float4(acc[0], acc[1], acc[2], acc[3]);
        __syncthreads();

        if (tid < 128) {
            #pragma unroll
            for (int gt = 0; gt < 4; ++gt) {
                const float s = pacc[0][lh][gt] + pacc[1][lh][gt];
                // s bounded -> exp never overflows fp32; LSE without max pass.
                float e = __expf(softplus_f(s + b2v));
                #pragma unroll
                for (int o = 32; o > 0; o >>= 1) e += __shfl_xor(e, o);
                if (lane == 0) red[wid][gt] = e;
            }
        }
        __syncthreads();
        if (tid == 0) {
            #pragma unroll
            for (int gt = 0; gt < 4; ++gt)
                negE[unit * 8 + half * 4 + gt] = red[0][gt] + red[1][gt];
        }

        // pos rows: 2 per block, waves 0..1
        if (wid < 2) {
            const int row = bid * 2 + wid;
            const float4* ra = (const float4*)(P0a + (size_t)row * GSTR);
            const float4* rb = (const float4*)(P0b + (size_t)row * GSTR);
            float d = 0.f;
            for (int k4 = lane; k4 < 75; k4 += 64) {
                const float4 a = ra[k4], b = rb[k4];
                const float4 bb = *(const float4*)(b1 + k4 * 4);
                const float4 wv = *(const float4*)&w2s[k4 * 4];
                d += fmaxf(a.x + b.x + bb.x, 0.f) * wv.x
                   + fmaxf(a.y + b.y + bb.y, 0.f) * wv.y
                   + fmaxf(a.z + b.z + bb.z, 0.f) * wv.z
                   + fmaxf(a.w + b.w + bb.w, 0.f) * wv.w;
            }
            #pragma unroll
            for (int o = 32; o > 0; o >>= 1) d += __shfl_xor(d, o);
            if (lane == 0) redp[wid] = softplus_f(d + b2v);
        }
        __syncthreads();
        if (tid == 0) posP[bid] = redp[0] + redp[1];
    }
    __threadfence();
    gg.sync();

    // ---------------- Phase D: final reduce (block 0) ----------------
    if (bid == 0) {
        float v = 0.f;
        for (int i = tid; i < 2048; i += 256) {
            const int u = i >> 2, gt = i & 3;
            v += __logf(negE[u * 8 + gt] + negE[u * 8 + 4 + gt]);
        }
        v -= posP[tid] + posP[tid + 256] + posP[tid + 512] + posP[tid + 768];
        #pragma unroll
        for (int o = 32; o > 0; o >>= 1) v += __shfl_xor(v, o);
        if (lane == 0) fin[wid] = v;
        __syncthreads();
        if (tid == 0)
            out[0] = (fin[0] + fin[1] + fin[2] + fin[3]) * (1.f / 2048.f);
    }
}

extern "C" void kernel_launch(void* const* d_in, const int* in_sizes, int n_in,
                              void* d_out, int out_size, void* d_ws, size_t ws_size,
                              hipStream_t stream)
{
    const float* pl = (const float*)d_in[0];
    const float* pg = (const float*)d_in[1];
    const float* nl = (const float*)d_in[2];
    const float* ng = (const float*)d_in[3];
    const float* W1 = (const float*)d_in[4];
    const float* b1 = (const float*)d_in[5];
    const float* W2 = (const float*)d_in[6];
    const float* b2 = (const float*)d_in[7];

    char* ws = (char*)d_ws;
    unsigned short* Aneg = (unsigned short*)(ws);                 // 4 MB
    unsigned short* Apos = (unsigned short*)(ws + (4u << 20));    // 4 MB
    unsigned short* Wt   = (unsigned short*)(ws + (8u << 20));    // 640 KB
    float* LP4  = (float*)(ws + (9u << 20));                      // 2.62 MB
    float* GPB  = (float*)(ws + (12u << 20));                     // 2.49 MB
    float* P0a  = (float*)(ws + (15u << 20));                     // 2.49 MB
    float* P0b  = (float*)(ws + (18u << 20));                     // 2.49 MB
    float* negE = (float*)(ws + (21u << 20));                     // 4096 f
    float* posP = negE + 4096;                                    // 1024 f
    float* out  = (float*)d_out;

    void* args[] = {
        (void*)&pl, (void*)&pg, (void*)&nl, (void*)&ng,
        (void*)&W1, (void*)&b1, (void*)&W2, (void*)&b2,
        (void*)&Aneg, (void*)&Apos, (void*)&Wt,
        (void*)&LP4, (void*)&GPB, (void*)&P0a, (void*)&P0b,
        (void*)&negE, (void*)&posP, (void*)&out
    };
    hipLaunchCooperativeKernel((void*)infonce_all, dim3(GRID), dim3(256),
                               args, 0, stream);
}

// Round 8
// 80.678 us; speedup vs baseline: 8.3580x; 8.3580x over previous
//
#include <hip/hip_runtime.h>
#include <math.h>

#define NR   2048
#define XD   512
#define HID  300
#define BS   256
#define NPAD 320
#define KTOT 1024
#define GSTR 304          // row stride for GPB/P0a/P0b (float4-aligned)
#define NBLK 1056         // fused grid: 1024 neg (512 units x 2 l-halves) + 32 pos

typedef __attribute__((ext_vector_type(8))) short bf16x8;
typedef __attribute__((ext_vector_type(4))) float f32x4;

__device__ __forceinline__ float softplus_f(float x) {
    return fmaxf(x, 0.f) + log1pf(__expf(-fabsf(x)));
}
__device__ __forceinline__ unsigned short f2bf(float f) {
    unsigned int u = __float_as_uint(f);
    u += 0x7FFFu + ((u >> 16) & 1u);   // RNE
    return (unsigned short)(u >> 16);
}

// grid.x = 2048 (Aneg rows) + 2048 (Apos rows) + 320 (Wt tiles)
__global__ __launch_bounds__(256) void convert(
    const float* __restrict__ pl, const float* __restrict__ pg,
    const float* __restrict__ nl, const float* __restrict__ ng,
    const float* __restrict__ W1,
    unsigned short* __restrict__ Aneg, unsigned short* __restrict__ Apos,
    unsigned short* __restrict__ Wt, unsigned int* __restrict__ counter)
{
    const int b = blockIdx.x, tid = threadIdx.x;
    if (b == 0 && tid == 0) *counter = 0u;   // reset ticket each call
    if (b < 4096) {
        const int m = (b < 2048) ? b : b - 2048;
        const float* lo = (b < 2048) ? nl : pl;
        const float* hi = (b < 2048) ? ng : pg;
        unsigned short* dst = (b < 2048) ? Aneg : Apos;
        const int kq = tid * 4;
        const float4 v = (kq < XD) ? *(const float4*)(lo + m * XD + kq)
                                   : *(const float4*)(hi + m * XD + kq - XD);
        ushort4 o;
        o.x = f2bf(v.x); o.y = f2bf(v.y); o.z = f2bf(v.z); o.w = f2bf(v.w);
        *(ushort4*)(dst + m * KTOT + kq) = o;
    } else {
        // W1 [1024][300] -> Wt [320][1024] bf16, zero-padded rows 300..319
        __shared__ unsigned short ts[16][72];
        const int t = b - 4096;
        const int nt = t % 20, kt = t / 20;   // 20 n-tiles x 16 k-tiles
        const int n = nt * 16 + (tid & 15);
        const int kl = tid >> 4;
        #pragma unroll
        for (int j = 0; j < 4; ++j) {
            const int k = kt * 64 + kl * 4 + j;
            ts[tid & 15][kl * 4 + j] = f2bf((n < HID) ? W1[k * HID + n] : 0.f);
        }
        __syncthreads();
        const int nw = tid >> 4, kw = (tid & 15) * 4;
        ushort4 o;
        o.x = ts[nw][kw]; o.y = ts[nw][kw + 1]; o.z = ts[nw][kw + 2]; o.w = ts[nw][kw + 3];
        *(ushort4*)(Wt + (nt * 16 + nw) * KTOT + kt * 64 + kw) = o;
    }
}

// One wave per block, 32x32 tile of 16x16x32 MFMAs, all jobs K=512.
// job 0: LP4  = nl @ W1l               (k<512,  scattered [k/4][l][4])
// job 1: GPB  = ng @ W1g + b1          (k>=512)
// job 2: P0a  = pl @ W1l               (k<512,  raw)
// job 3: P0b  = pg @ W1g               (k>=512, raw)
__global__ __launch_bounds__(64) void mfma_gemm(
    const unsigned short* __restrict__ Aneg, const unsigned short* __restrict__ Apos,
    const unsigned short* __restrict__ Wt, const float* __restrict__ b1,
    float* __restrict__ LP4, float* __restrict__ GPB,
    float* __restrict__ P0a, float* __restrict__ P0b)
{
    const int job = blockIdx.z;
    const int m0 = blockIdx.x * 32, n0 = blockIdx.y * 32;
    const int lane = threadIdx.x;
    const int r = lane & 15, g = lane >> 4;

    const unsigned short* A = (job >= 2) ? Apos : Aneg;
    const int kbeg = (job & 1) ? XD : 0;

    const unsigned short* a0p = A  + (m0 + r) * KTOT + kbeg + 8 * g;
    const unsigned short* a1p = a0p + 16 * KTOT;
    const unsigned short* b0p = Wt + (n0 + r) * KTOT + kbeg + 8 * g;
    const unsigned short* b1p = b0p + 16 * KTOT;

    f32x4 acc00 = {0,0,0,0}, acc01 = {0,0,0,0}, acc10 = {0,0,0,0}, acc11 = {0,0,0,0};

    #pragma unroll 8
    for (int k = 0; k < XD; k += 32) {
        const bf16x8 a0 = *(const bf16x8*)(a0p + k);
        const bf16x8 a1 = *(const bf16x8*)(a1p + k);
        const bf16x8 w0 = *(const bf16x8*)(b0p + k);
        const bf16x8 w1 = *(const bf16x8*)(b1p + k);
        acc00 = __builtin_amdgcn_mfma_f32_16x16x32_bf16(a0, w0, acc00, 0, 0, 0);
        acc01 = __builtin_amdgcn_mfma_f32_16x16x32_bf16(a0, w1, acc01, 0, 0, 0);
        acc10 = __builtin_amdgcn_mfma_f32_16x16x32_bf16(a1, w0, acc10, 0, 0, 0);
        acc11 = __builtin_amdgcn_mfma_f32_16x16x32_bf16(a1, w1, acc11, 0, 0, 0);
    }

    f32x4 accs[2][2] = {{acc00, acc01}, {acc10, acc11}};
    #pragma unroll
    for (int mi = 0; mi < 2; ++mi) {
        #pragma unroll
        for (int ni = 0; ni < 2; ++ni) {
            const int n = n0 + ni * 16 + r;
            const int mb = m0 + mi * 16 + 4 * g;
            const f32x4 v = accs[mi][ni];
            if (job == 0) {
                float* base = LP4 + ((size_t)(n >> 2) * NR + mb) * 4 + (n & 3);
                base[0] = v[0]; base[4] = v[1]; base[8] = v[2]; base[12] = v[3];
            } else if (n < HID) {
                const float bias = (job == 1) ? b1[n] : 0.f;
                float* out = (job == 1) ? GPB : ((job == 2) ? P0a : P0b);
                #pragma unroll
                for (int j = 0; j < 4; ++j)
                    out[(size_t)(mb + j) * GSTR + n] = v[j] + bias;
            }
        }
    }
}

// grid 1056:
//  bid<1024: neg. unit = bid>>1 (chunk = unit>>6, 4 g-rows = (unit&63)*4),
//            l-half = bid&1. Threads: lh = tid&127 (l), kh = tid>>7 (k-half).
//            Uses w*relu(t) = w't + w'|t| (w'=w/2): inner = add + fma(|.|).
//  bid>=1024: pos, 64 rows per block, thread = (row, k-quarter).
// Last block (ticket) does logs + final sum.
__global__ __launch_bounds__(256, 4) void fused(
    const float* __restrict__ LP4, const float* __restrict__ GPB,
    const float* __restrict__ P0a, const float* __restrict__ P0b,
    const float* __restrict__ b1, const float* __restrict__ W2,
    const float* __restrict__ b2,
    float* __restrict__ negE, float* __restrict__ posP,
    unsigned int* __restrict__ counter, float* __restrict__ out)
{
    __shared__ __align__(16) float w2s[HID];
    __shared__ __align__(16) float gbs[4][HID];
    __shared__ __align__(16) float pacc[2][128][4];
    __shared__ float sC[4];
    __shared__ float red[4][4];
    __shared__ int sh_last;
    const int tid = threadIdx.x;
    const int bid = blockIdx.x;
    const int wid = tid >> 6, lane = tid & 63;
    const float b2v = b2[0];

    if (bid < 1024) {
        // ---------------- negative term ----------------
        const int unit = bid >> 1, lhalf = bid & 1;
        const int chunk = unit >> 6, g0 = (unit & 63) * 4;
        const float* gp = GPB + (size_t)(chunk * BS + g0) * GSTR;
        for (int idx = tid; idx < HID; idx += 256) {
            w2s[idx] = 0.5f * W2[idx];
            gbs[0][idx] = gp[idx];
            gbs[1][idx] = gp[GSTR + idx];
            gbs[2][idx] = gp[2 * GSTR + idx];
            gbs[3][idx] = gp[3 * GSTR + idx];
        }
        __syncthreads();

        // C_g = sum_k w'_k * gp[g][k] ; wave wid handles g-row wid
        {
            float c = 0.f;
            int k4 = lane;
            if (k4 < 75) {
                const float4 g4 = *(const float4*)&gbs[wid][k4 * 4];
                const float4 w4 = *(const float4*)&w2s[k4 * 4];
                c += g4.x * w4.x + g4.y * w4.y + g4.z * w4.z + g4.w * w4.w;
            }
            k4 = lane + 64;
            if (k4 < 75) {
                const float4 g4 = *(const float4*)&gbs[wid][k4 * 4];
                const float4 w4 = *(const float4*)&w2s[k4 * 4];
                c += g4.x * w4.x + g4.y * w4.y + g4.z * w4.z + g4.w * w4.w;
            }
            #pragma unroll
            for (int o = 32; o > 0; o >>= 1) c += __shfl_xor(c, o);
            if (lane == 0) sC[wid] = c;
        }

        const int lh = tid & 127, kh = tid >> 7;
        const int lg = chunk * BS + lhalf * 128 + lh;
        const float4* lp4 = (const float4*)LP4 + lg;
        const int k4beg = kh ? 38 : 0;
        const int k4end = kh ? 75 : 38;

        float acc[4] = {0.f, 0.f, 0.f, 0.f};
        float q = 0.f;   // sum_k w'_k * lp[l][k] over this k-range
        // 2-deep register pipeline on LP (prefetch index <= 76 < 80-slot pad)
        float4 a0 = lp4[(size_t)k4beg * NR];
        float4 a1 = lp4[(size_t)(k4beg + 1) * NR];
        for (int k4 = k4beg; k4 < k4end; ++k4) {
            const float4 nx = lp4[(size_t)(k4 + 2) * NR];
            const float4 w4 = *(const float4*)&w2s[k4 * 4];
            q = fmaf(w4.x, a0.x, q); q = fmaf(w4.y, a0.y, q);
            q = fmaf(w4.z, a0.z, q); q = fmaf(w4.w, a0.w, q);
            #pragma unroll
            for (int gt = 0; gt < 4; ++gt) {
                const float4 g4 = *(const float4*)&gbs[gt][k4 * 4];
                acc[gt] = fmaf(fabsf(g4.x + a0.x), w4.x, acc[gt]);
                acc[gt] = fmaf(fabsf(g4.y + a0.y), w4.y, acc[gt]);
                acc[gt] = fmaf(fabsf(g4.z + a0.z), w4.z, acc[gt]);
                acc[gt] = fmaf(fabsf(g4.w + a0.w), w4.w, acc[gt]);
            }
            a0 = a1; a1 = nx;
        }
        __syncthreads();   // sC ready; also orders pacc reuse
        *(float4*)&pacc[kh][lh][0] =
            make_float4(acc[0] + q, acc[1] + q, acc[2] + q, acc[3] + q);
        __syncthreads();

        if (tid < 128) {
            #pragma unroll
            for (int gt = 0; gt < 4; ++gt) {
                const float s = sC[gt] + pacc[0][lh][gt] + pacc[1][lh][gt];
                // s bounded -> exp never overflows fp32; LSE without max pass
                float e = __expf(softplus_f(s + b2v));
                #pragma unroll
                for (int o = 32; o > 0; o >>= 1) e += __shfl_xor(e, o);
                if (lane == 0) red[wid][gt] = e;
            }
        }
        __syncthreads();
        if (tid == 0) {
            #pragma unroll
            for (int gt = 0; gt < 4; ++gt)
                negE[unit * 8 + lhalf * 4 + gt] = red[0][gt] + red[1][gt];
        }
    } else {
        // ---------------- positive term: 64 rows/block ----------------
        for (int idx = tid; idx < HID; idx += 256) {
            w2s[idx] = W2[idx];
            gbs[0][idx] = b1[idx];
        }
        __syncthreads();
        const int rl = tid >> 2, qq = tid & 3;
        const int i = (bid - 1024) * 64 + rl;
        const int q0 = qq * 19;
        const int q1 = (qq == 3) ? HID / 4 : q0 + 19;
        const float4* ra = (const float4*)(P0a + (size_t)i * GSTR);
        const float4* rb = (const float4*)(P0b + (size_t)i * GSTR);
        float acc = 0.f;
        for (int k4 = q0; k4 < q1; ++k4) {
            const float4 a = ra[k4], b = rb[k4];
            const float4 bb = *(const float4*)&gbs[0][k4 * 4];
            const float4 wv = *(const float4*)&w2s[k4 * 4];
            acc += fmaxf(a.x + b.x + bb.x, 0.f) * wv.x
                 + fmaxf(a.y + b.y + bb.y, 0.f) * wv.y
                 + fmaxf(a.z + b.z + bb.z, 0.f) * wv.z
                 + fmaxf(a.w + b.w + bb.w, 0.f) * wv.w;
        }
        acc += __shfl_xor(acc, 1);
        acc += __shfl_xor(acc, 2);
        float sp = (qq == 0) ? softplus_f(acc + b2v) : 0.f;
        #pragma unroll
        for (int o = 32; o > 0; o >>= 1) sp += __shfl_xor(sp, o);
        if ((tid & 63) == 0) red[wid][0] = sp;
        __syncthreads();
        if (tid == 0)
            posP[bid - 1024] = red[0][0] + red[1][0] + red[2][0] + red[3][0];
    }

    // ---- last-block finalize (device-scope ticket) ----
    if (tid == 0) {
        __threadfence();
        const unsigned t = atomicAdd(counter, 1u);
        sh_last = (t == NBLK - 1) ? 1 : 0;
    }
    __syncthreads();
    if (sh_last) {
        __threadfence();
        const volatile float* ne = (const volatile float*)negE;
        const volatile float* pp = (const volatile float*)posP;
        float v = 0.f;
        for (int i = tid; i < 2048; i += 256) {
            const int u = i >> 2, gt = i & 3;
            v += __logf(ne[u * 8 + gt] + ne[u * 8 + 4 + gt]);
        }
        if (tid < 32) v -= pp[tid];
        #pragma unroll
        for (int o = 32; o > 0; o >>= 1) v += __shfl_xor(v, o);
        if (lane == 0) red[wid][0] = v;
        __syncthreads();
        if (tid == 0)
            out[0] = (red[0][0] + red[1][0] + red[2][0] + red[3][0]) * (1.f / 2048.f);
    }
}

extern "C" void kernel_launch(void* const* d_in, const int* in_sizes, int n_in,
                              void* d_out, int out_size, void* d_ws, size_t ws_size,
                              hipStream_t stream)
{
    const float* pl = (const float*)d_in[0];
    const float* pg = (const float*)d_in[1];
    const float* nl = (const float*)d_in[2];
    const float* ng = (const float*)d_in[3];
    const float* W1 = (const float*)d_in[4];
    const float* b1 = (const float*)d_in[5];
    const float* W2 = (const float*)d_in[6];
    const float* b2 = (const float*)d_in[7];

    char* ws = (char*)d_ws;
    unsigned short* Aneg = (unsigned short*)(ws);                 // 4 MB
    unsigned short* Apos = (unsigned short*)(ws + (4u << 20));    // 4 MB
    unsigned short* Wt   = (unsigned short*)(ws + (8u << 20));    // 640 KB
    float* LP4  = (float*)(ws + (9u << 20));                      // 2.62 MB
    float* GPB  = (float*)(ws + (12u << 20));                     // 2.49 MB
    float* P0a  = (float*)(ws + (15u << 20));                     // 2.49 MB
    float* P0b  = (float*)(ws + (18u << 20));                     // 2.49 MB
    float* negE = (float*)(ws + (21u << 20));                     // 4096 f
    float* posP = negE + 4096;                                    // 32 f
    unsigned int* counter = (unsigned int*)(ws + (21u << 20) + 65536);
    float* out  = (float*)d_out;

    hipLaunchKernelGGL(convert, dim3(4096 + 320), dim3(256), 0, stream,
                       pl, pg, nl, ng, W1, Aneg, Apos, Wt, counter);
    hipLaunchKernelGGL(mfma_gemm, dim3(NR / 32, NPAD / 32, 4), dim3(64), 0, stream,
                       Aneg, Apos, Wt, b1, LP4, GPB, P0a, P0b);
    hipLaunchKernelGGL(fused, dim3(NBLK), dim3(256), 0, stream,
                       LP4, GPB, P0a, P0b, b1, W2, b2, negE, posP, counter, out);
}

// Round 9
// 67.698 us; speedup vs baseline: 9.9604x; 1.1917x over previous
//
#include <hip/hip_runtime.h>
#include <math.h>

#define NR   2048
#define XD   512
#define HID  300
#define BS   256
#define NPAD 320
#define KTOT 1024
#define GSTR 304          // row stride for GPB/P0a/P0b (float4-aligned)
#define NBLK 544          // fused grid: 512 neg units + 32 pos

typedef __attribute__((ext_vector_type(8))) short bf16x8;
typedef __attribute__((ext_vector_type(4))) float f32x4;

__device__ __forceinline__ float softplus_f(float x) {
    return fmaxf(x, 0.f) + log1pf(__expf(-fabsf(x)));
}
__device__ __forceinline__ unsigned short f2bf(float f) {
    unsigned int u = __float_as_uint(f);
    u += 0x7FFFu + ((u >> 16) & 1u);   // RNE
    return (unsigned short)(u >> 16);
}

// grid.x = 2048 (Aneg rows) + 2048 (Apos rows) + 320 (Wt tiles)
__global__ __launch_bounds__(256) void convert(
    const float* __restrict__ pl, const float* __restrict__ pg,
    const float* __restrict__ nl, const float* __restrict__ ng,
    const float* __restrict__ W1,
    unsigned short* __restrict__ Aneg, unsigned short* __restrict__ Apos,
    unsigned short* __restrict__ Wt, unsigned int* __restrict__ counter)
{
    const int b = blockIdx.x, tid = threadIdx.x;
    if (b == 0 && tid == 0) *counter = 0u;   // reset ticket each call
    if (b < 4096) {
        const int m = (b < 2048) ? b : b - 2048;
        const float* lo = (b < 2048) ? nl : pl;
        const float* hi = (b < 2048) ? ng : pg;
        unsigned short* dst = (b < 2048) ? Aneg : Apos;
        const int kq = tid * 4;
        const float4 v = (kq < XD) ? *(const float4*)(lo + m * XD + kq)
                                   : *(const float4*)(hi + m * XD + kq - XD);
        ushort4 o;
        o.x = f2bf(v.x); o.y = f2bf(v.y); o.z = f2bf(v.z); o.w = f2bf(v.w);
        *(ushort4*)(dst + m * KTOT + kq) = o;
    } else {
        // W1 [1024][300] -> Wt [320][1024] bf16, zero-padded rows 300..319
        __shared__ unsigned short ts[16][72];
        const int t = b - 4096;
        const int nt = t % 20, kt = t / 20;   // 20 n-tiles x 16 k-tiles
        const int n = nt * 16 + (tid & 15);
        const int kl = tid >> 4;
        #pragma unroll
        for (int j = 0; j < 4; ++j) {
            const int k = kt * 64 + kl * 4 + j;
            ts[tid & 15][kl * 4 + j] = f2bf((n < HID) ? W1[k * HID + n] : 0.f);
        }
        __syncthreads();
        const int nw = tid >> 4, kw = (tid & 15) * 4;
        ushort4 o;
        o.x = ts[nw][kw]; o.y = ts[nw][kw + 1]; o.z = ts[nw][kw + 2]; o.w = ts[nw][kw + 3];
        *(ushort4*)(Wt + (nt * 16 + nw) * KTOT + kt * 64 + kw) = o;
    }
}

// One wave per block, 32x32 tile of 16x16x32 MFMAs, all jobs K=512.
// job 0: LP4  = nl @ W1l               (k<512,  scattered [k/4][l][4])
// job 1: GPB  = ng @ W1g + b1          (k>=512)
// job 2: P0a  = pl @ W1l               (k<512,  raw)
// job 3: P0b  = pg @ W1g               (k>=512, raw)
__global__ __launch_bounds__(64) void mfma_gemm(
    const unsigned short* __restrict__ Aneg, const unsigned short* __restrict__ Apos,
    const unsigned short* __restrict__ Wt, const float* __restrict__ b1,
    float* __restrict__ LP4, float* __restrict__ GPB,
    float* __restrict__ P0a, float* __restrict__ P0b)
{
    const int job = blockIdx.z;
    const int m0 = blockIdx.x * 32, n0 = blockIdx.y * 32;
    const int lane = threadIdx.x;
    const int r = lane & 15, g = lane >> 4;

    const unsigned short* A = (job >= 2) ? Apos : Aneg;
    const int kbeg = (job & 1) ? XD : 0;

    const unsigned short* a0p = A  + (m0 + r) * KTOT + kbeg + 8 * g;
    const unsigned short* a1p = a0p + 16 * KTOT;
    const unsigned short* b0p = Wt + (n0 + r) * KTOT + kbeg + 8 * g;
    const unsigned short* b1p = b0p + 16 * KTOT;

    f32x4 acc00 = {0,0,0,0}, acc01 = {0,0,0,0}, acc10 = {0,0,0,0}, acc11 = {0,0,0,0};

    #pragma unroll 8
    for (int k = 0; k < XD; k += 32) {
        const bf16x8 a0 = *(const bf16x8*)(a0p + k);
        const bf16x8 a1 = *(const bf16x8*)(a1p + k);
        const bf16x8 w0 = *(const bf16x8*)(b0p + k);
        const bf16x8 w1 = *(const bf16x8*)(b1p + k);
        acc00 = __builtin_amdgcn_mfma_f32_16x16x32_bf16(a0, w0, acc00, 0, 0, 0);
        acc01 = __builtin_amdgcn_mfma_f32_16x16x32_bf16(a0, w1, acc01, 0, 0, 0);
        acc10 = __builtin_amdgcn_mfma_f32_16x16x32_bf16(a1, w0, acc10, 0, 0, 0);
        acc11 = __builtin_amdgcn_mfma_f32_16x16x32_bf16(a1, w1, acc11, 0, 0, 0);
    }

    f32x4 accs[2][2] = {{acc00, acc01}, {acc10, acc11}};
    #pragma unroll
    for (int mi = 0; mi < 2; ++mi) {
        #pragma unroll
        for (int ni = 0; ni < 2; ++ni) {
            const int n = n0 + ni * 16 + r;
            const int mb = m0 + mi * 16 + 4 * g;
            const f32x4 v = accs[mi][ni];
            if (job == 0) {
                float* base = LP4 + ((size_t)(n >> 2) * NR + mb) * 4 + (n & 3);
                base[0] = v[0]; base[4] = v[1]; base[8] = v[2]; base[12] = v[3];
            } else if (n < HID) {
                const float bias = (job == 1) ? b1[n] : 0.f;
                float* out = (job == 1) ? GPB : ((job == 2) ? P0a : P0b);
                #pragma unroll
                for (int j = 0; j < 4; ++j)
                    out[(size_t)(mb + j) * GSTR + n] = v[j] + bias;
            }
        }
    }
}

// grid 544:
//  bid<512: neg unit (chunk = bid>>6, 4 g-rows = (bid&63)*4). 256 threads:
//           lane-l lh = tid&63, wave = k-quarter kh = tid>>6; each thread
//           carries 4 LP streams (l = lh+64j). Per k4: 5 LDS b128 reads
//           amortized over 16 (g,l) pairs. w*relu(t) = w't + w'|t| split.
//  bid>=512: pos, 64 rows per block, thread = (row, k-quarter).
// Last block (ticket) does logs + final sum.
__global__ __launch_bounds__(256, 2) void fused(
    const float* __restrict__ LP4, const float* __restrict__ GPB,
    const float* __restrict__ P0a, const float* __restrict__ P0b,
    const float* __restrict__ b1, const float* __restrict__ W2,
    const float* __restrict__ b2,
    float* __restrict__ negE, float* __restrict__ posP,
    unsigned int* __restrict__ counter, float* __restrict__ out)
{
    __shared__ __align__(16) float w2s[HID];
    __shared__ __align__(16) float gbs[4][HID];
    __shared__ __align__(16) float pacc[4][BS][4];   // [kh][l][gt], 16 KB
    __shared__ float sC[4];
    __shared__ float red[4][4];
    __shared__ int sh_last;
    const int tid = threadIdx.x;
    const int bid = blockIdx.x;
    const int wid = tid >> 6, lane = tid & 63;
    const float b2v = b2[0];

    if (bid < 512) {
        // ---------------- negative term ----------------
        const int chunk = bid >> 6, g0 = (bid & 63) * 4;
        const float* gp = GPB + (size_t)(chunk * BS + g0) * GSTR;
        for (int idx = tid; idx < HID; idx += 256) {
            w2s[idx] = 0.5f * W2[idx];
            gbs[0][idx] = gp[idx];
            gbs[1][idx] = gp[GSTR + idx];
            gbs[2][idx] = gp[2 * GSTR + idx];
            gbs[3][idx] = gp[3 * GSTR + idx];
        }
        __syncthreads();

        // sC[g] = sum_k w'_k * gp[g][k]  (wave wid handles g-row wid)
        {
            float c = 0.f;
            int k4 = lane;
            if (k4 < 75) {
                const float4 g4 = *(const float4*)&gbs[wid][k4 * 4];
                const float4 w4 = *(const float4*)&w2s[k4 * 4];
                c += g4.x * w4.x + g4.y * w4.y + g4.z * w4.z + g4.w * w4.w;
            }
            k4 = lane + 64;
            if (k4 < 75) {
                const float4 g4 = *(const float4*)&gbs[wid][k4 * 4];
                const float4 w4 = *(const float4*)&w2s[k4 * 4];
                c += g4.x * w4.x + g4.y * w4.y + g4.z * w4.z + g4.w * w4.w;
            }
            #pragma unroll
            for (int o = 32; o > 0; o >>= 1) c += __shfl_xor(c, o);
            if (lane == 0) sC[wid] = c;
        }

        // k-quarter for this wave: 19/19/19/18 k4's
        const int lh = lane, kh = wid;
        const int k4beg = (kh < 3) ? 19 * kh : 57;
        const int k4end = (kh < 3) ? k4beg + 19 : 75;
        const float4* lpb = (const float4*)LP4 + (chunk * BS + lh);

        float acc[4][4];      // [gt][j]
        float q[4] = {0.f, 0.f, 0.f, 0.f};
        #pragma unroll
        for (int gt = 0; gt < 4; ++gt)
            #pragma unroll
            for (int j = 0; j < 4; ++j) acc[gt][j] = 0.f;

        float4 a[4], nx[4];
        #pragma unroll
        for (int j = 0; j < 4; ++j)
            a[j] = lpb[(size_t)k4beg * NR + 64 * j];

        for (int k4 = k4beg; k4 < k4end; ++k4) {
            #pragma unroll
            for (int j = 0; j < 4; ++j)
                nx[j] = lpb[(size_t)(k4 + 1) * NR + 64 * j];   // idx <= 75 < 80 pad
            const float4 w4 = *(const float4*)&w2s[k4 * 4];
            #pragma unroll
            for (int j = 0; j < 4; ++j) {
                q[j] = fmaf(w4.x, a[j].x, q[j]);
                q[j] = fmaf(w4.y, a[j].y, q[j]);
                q[j] = fmaf(w4.z, a[j].z, q[j]);
                q[j] = fmaf(w4.w, a[j].w, q[j]);
            }
            #pragma unroll
            for (int gt = 0; gt < 4; ++gt) {
                const float4 g4 = *(const float4*)&gbs[gt][k4 * 4];
                #pragma unroll
                for (int j = 0; j < 4; ++j) {
                    acc[gt][j] = fmaf(fabsf(g4.x + a[j].x), w4.x, acc[gt][j]);
                    acc[gt][j] = fmaf(fabsf(g4.y + a[j].y), w4.y, acc[gt][j]);
                    acc[gt][j] = fmaf(fabsf(g4.z + a[j].z), w4.z, acc[gt][j]);
                    acc[gt][j] = fmaf(fabsf(g4.w + a[j].w), w4.w, acc[gt][j]);
                }
            }
            #pragma unroll
            for (int j = 0; j < 4; ++j) a[j] = nx[j];
        }

        #pragma unroll
        for (int j = 0; j < 4; ++j)
            *(float4*)&pacc[kh][lh + 64 * j][0] =
                make_float4(acc[0][j] + q[j], acc[1][j] + q[j],
                            acc[2][j] + q[j], acc[3][j] + q[j]);
        __syncthreads();

        // combine: thread tid = l; s[gt] = sC[gt] + sum_kh pacc[kh][l][gt]
        {
            float s0 = sC[0], s1 = sC[1], s2 = sC[2], s3 = sC[3];
            #pragma unroll
            for (int k = 0; k < 4; ++k) {
                const float4 p = *(const float4*)&pacc[k][tid][0];
                s0 += p.x; s1 += p.y; s2 += p.z; s3 += p.w;
            }
            float e[4];
            e[0] = __expf(softplus_f(s0 + b2v));
            e[1] = __expf(softplus_f(s1 + b2v));
            e[2] = __expf(softplus_f(s2 + b2v));
            e[3] = __expf(softplus_f(s3 + b2v));
            #pragma unroll
            for (int gt = 0; gt < 4; ++gt) {
                float v = e[gt];
                #pragma unroll
                for (int o = 32; o > 0; o >>= 1) v += __shfl_xor(v, o);
                if (lane == 0) red[wid][gt] = v;
            }
        }
        __syncthreads();
        if (tid == 0) {
            #pragma unroll
            for (int gt = 0; gt < 4; ++gt)
                negE[bid * 4 + gt] = red[0][gt] + red[1][gt] + red[2][gt] + red[3][gt];
        }
    } else {
        // ---------------- positive term: 64 rows/block ----------------
        for (int idx = tid; idx < HID; idx += 256) {
            w2s[idx] = W2[idx];
            gbs[0][idx] = b1[idx];
        }
        __syncthreads();
        const int rl = tid >> 2, qq = tid & 3;
        const int i = (bid - 512) * 64 + rl;
        const int q0 = qq * 19;
        const int q1 = (qq == 3) ? HID / 4 : q0 + 19;
        const float4* ra = (const float4*)(P0a + (size_t)i * GSTR);
        const float4* rb = (const float4*)(P0b + (size_t)i * GSTR);
        float acc = 0.f;
        for (int k4 = q0; k4 < q1; ++k4) {
            const float4 aa = ra[k4], bb4 = rb[k4];
            const float4 bb = *(const float4*)&gbs[0][k4 * 4];
            const float4 wv = *(const float4*)&w2s[k4 * 4];
            acc += fmaxf(aa.x + bb4.x + bb.x, 0.f) * wv.x
                 + fmaxf(aa.y + bb4.y + bb.y, 0.f) * wv.y
                 + fmaxf(aa.z + bb4.z + bb.z, 0.f) * wv.z
                 + fmaxf(aa.w + bb4.w + bb.w, 0.f) * wv.w;
        }
        acc += __shfl_xor(acc, 1);
        acc += __shfl_xor(acc, 2);
        float sp = (qq == 0) ? softplus_f(acc + b2v) : 0.f;
        #pragma unroll
        for (int o = 32; o > 0; o >>= 1) sp += __shfl_xor(sp, o);
        if (lane == 0) red[wid][0] = sp;
        __syncthreads();
        if (tid == 0)
            posP[bid - 512] = red[0][0] + red[1][0] + red[2][0] + red[3][0];
    }

    // ---- last-block finalize (device-scope ticket) ----
    if (tid == 0) {
        __threadfence();
        const unsigned t = atomicAdd(counter, 1u);
        sh_last = (t == NBLK - 1) ? 1 : 0;
    }
    __syncthreads();
    if (sh_last) {
        __threadfence();
        const volatile float* ne = (const volatile float*)negE;
        const volatile float* pp = (const volatile float*)posP;
        float v = 0.f;
        for (int i = tid; i < 2048; i += 256)
            v += __logf(ne[i]);
        if (tid < 32) v -= pp[tid];
        #pragma unroll
        for (int o = 32; o > 0; o >>= 1) v += __shfl_xor(v, o);
        if (lane == 0) red[wid][0] = v;
        __syncthreads();
        if (tid == 0)
            out[0] = (red[0][0] + red[1][0] + red[2][0] + red[3][0]) * (1.f / 2048.f);
    }
}

extern "C" void kernel_launch(void* const* d_in, const int* in_sizes, int n_in,
                              void* d_out, int out_size, void* d_ws, size_t ws_size,
                              hipStream_t stream)
{
    const float* pl = (const float*)d_in[0];
    const float* pg = (const float*)d_in[1];
    const float* nl = (const float*)d_in[2];
    const float* ng = (const float*)d_in[3];
    const float* W1 = (const float*)d_in[4];
    const float* b1 = (const float*)d_in[5];
    const float* W2 = (const float*)d_in[6];
    const float* b2 = (const float*)d_in[7];

    char* ws = (char*)d_ws;
    unsigned short* Aneg = (unsigned short*)(ws);                 // 4 MB
    unsigned short* Apos = (unsigned short*)(ws + (4u << 20));    // 4 MB
    unsigned short* Wt   = (unsigned short*)(ws + (8u << 20));    // 640 KB
    float* LP4  = (float*)(ws + (9u << 20));                      // 2.62 MB
    float* GPB  = (float*)(ws + (12u << 20));                     // 2.49 MB
    float* P0a  = (float*)(ws + (15u << 20));                     // 2.49 MB
    float* P0b  = (float*)(ws + (18u << 20));                     // 2.49 MB
    float* negE = (float*)(ws + (21u << 20));                     // 2048 f
    float* posP = negE + 2048;                                    // 32 f
    unsigned int* counter = (unsigned int*)(ws + (21u << 20) + 65536);
    float* out  = (float*)d_out;

    hipLaunchKernelGGL(convert, dim3(4096 + 320), dim3(256), 0, stream,
                       pl, pg, nl, ng, W1, Aneg, Apos, Wt, counter);
    hipLaunchKernelGGL(mfma_gemm, dim3(NR / 32, NPAD / 32, 4), dim3(64), 0, stream,
                       Aneg, Apos, Wt, b1, LP4, GPB, P0a, P0b);
    hipLaunchKernelGGL(fused, dim3(NBLK), dim3(256), 0, stream,
                       LP4, GPB, P0a, P0b, b1, W2, b2, negE, posP, counter, out);
}